// Round 4
// baseline (878.569 us; speedup 1.0000x reference)
//
#include <hip/hip_runtime.h>
#include <math.h>

#define HH 1024
#define VV 50257
#define NBLK 2048
#define NWAVE (NBLK * 4)  // 8192 waves

__device__ __forceinline__ float wave_allreduce_sum(float v) {
#pragma unroll
    for (int off = 1; off < 64; off <<= 1) v += __shfl_xor(v, off, 64);
    return v;
}

__device__ __forceinline__ void lse_comb(float& m, float& s, float om, float os) {
    float M = fmaxf(m, om);
    s = s * expf(m - M) + os * expf(om - M);
    m = M;
}

__device__ __forceinline__ float sigmoidf(float x) { return 1.0f / (1.0f + expf(-x)); }

// One persistent kernel, grid EXACTLY 2048 blocks x 256 threads = 8 blocks/CU
// on 256 CUs, all co-resident (VGPR capped by launch_bounds, LDS ~48B).
__global__ __launch_bounds__(256, 8) void k_fused(
    const int* __restrict__ x, const float* __restrict__ emb,
    const float* __restrict__ h0, const float* __restrict__ c0,
    const float* __restrict__ w_ih, const float* __restrict__ w_hh,
    const float* __restrict__ b_ih, const float* __restrict__ b_hh,
    const float* __restrict__ w_out, const float* __restrict__ b_out,
    float* __restrict__ out, float* __restrict__ hbuf,
    float* __restrict__ pm, float* __restrict__ ps,
    unsigned int* __restrict__ ctr) {
    __shared__ float sg[4];
    __shared__ float sm[4], ss[4];
    const int b = blockIdx.x;
    const int w = threadIdx.x >> 6;
    const int lane = threadIdx.x & 63;
    const int wave_id = b * 4 + w;

    float pf[16];  // prefetched first w_out row chunk (non-gate blocks only)

    if (b < 1024) {
        // ---- Phase A (gate blocks): gates + cell for hidden index j = b ----
        const int j = b;
        const int row = w * HH + j;
        const float* e  = emb + (size_t)x[0] * HH;
        const float* wi = w_ih + (size_t)row * HH;
        const float* wh = w_hh + (size_t)row * HH;
        float acc = 0.0f;
#pragma unroll
        for (int k = 0; k < 4; ++k) {
            int idx = k * 256 + lane * 4;
            float4 wiv = *reinterpret_cast<const float4*>(wi + idx);
            float4 whv = *reinterpret_cast<const float4*>(wh + idx);
            float4 ev  = *reinterpret_cast<const float4*>(e + idx);
            float4 hv  = *reinterpret_cast<const float4*>(h0 + idx);
            ev.x = fmaxf(ev.x, 0.0f); ev.y = fmaxf(ev.y, 0.0f);
            ev.z = fmaxf(ev.z, 0.0f); ev.w = fmaxf(ev.w, 0.0f);
            acc += wiv.x * ev.x + wiv.y * ev.y + wiv.z * ev.z + wiv.w * ev.w;
            acc += whv.x * hv.x + whv.y * hv.y + whv.z * hv.z + whv.w * hv.w;
        }
        acc = wave_allreduce_sum(acc);
        if (lane == 0) sg[w] = acc + b_ih[row] + b_hh[row];
        __syncthreads();
        if (threadIdx.x == 0) {
            float ig = sigmoidf(sg[0]);
            float fg = sigmoidf(sg[1]);
            float gg = tanhf(sg[2]);
            float og = sigmoidf(sg[3]);
            float c = fg * c0[j] + ig * gg;
            float h = og * tanhf(c);
            hbuf[j] = h;
            out[VV + j] = h;
            out[VV + HH + j] = c;
            __threadfence();  // release h before counting
            __hip_atomic_fetch_add(&ctr[0], 1u, __ATOMIC_RELEASE, __HIP_MEMORY_SCOPE_AGENT);
        }
    } else {
        // ---- Phase A (logit blocks): prefetch first w_out row into regs ----
        const float* wr = w_out + (size_t)wave_id * HH + lane * 4;
#pragma unroll
        for (int k = 0; k < 4; ++k) {
            float4 v = *reinterpret_cast<const float4*>(wr + k * 256);
            pf[k * 4 + 0] = v.x; pf[k * 4 + 1] = v.y;
            pf[k * 4 + 2] = v.z; pf[k * 4 + 3] = v.w;
        }
    }

    // ---- wait until h is ready ----
    if (threadIdx.x == 0) {
        while (__hip_atomic_load(&ctr[0], __ATOMIC_ACQUIRE, __HIP_MEMORY_SCOPE_AGENT) < 1024u)
            __builtin_amdgcn_s_sleep(2);
    }
    __syncthreads();
    __threadfence();  // ensure this thread's subsequent loads see fresh hbuf

    // ---- Phase B: wave-per-row logits with online LSE (uniform on all lanes) ----
    float m = -1e30f, s = 0.0f;
    float lv[7];
#pragma unroll
    for (int c = 0; c < 7; ++c) {
        int row = wave_id + c * NWAVE;
        if (row < VV) {
            const float* wr = w_out + (size_t)row * HH + lane * 4;
            float acc = 0.0f;
#pragma unroll
            for (int k = 0; k < 4; ++k) {
                float4 wv;
                if (c == 0 && b >= 1024) {
                    wv = make_float4(pf[k * 4 + 0], pf[k * 4 + 1], pf[k * 4 + 2], pf[k * 4 + 3]);
                } else {
                    wv = *reinterpret_cast<const float4*>(wr + k * 256);
                }
                float4 hv = *reinterpret_cast<const float4*>(hbuf + k * 256 + lane * 4);
                acc += wv.x * hv.x + wv.y * hv.y + wv.z * hv.z + wv.w * hv.w;
            }
            acc = wave_allreduce_sum(acc);  // all lanes hold the dot product
            float v = acc + b_out[row];
            lv[c] = v;
            if (v > m) {  // wave-uniform branch
                s = s * expf(m - v) + 1.0f;
                m = v;
            } else {
                s += expf(v - m);
            }
        }
    }

    // ---- block combine (m,s) and publish ----
    if (lane == 0) { sm[w] = m; ss[w] = s; }
    __syncthreads();
    if (threadIdx.x == 0) {
        float M = sm[0], S = ss[0];
#pragma unroll
        for (int q = 1; q < 4; ++q) lse_comb(M, S, sm[q], ss[q]);
        pm[b] = M;
        ps[b] = S;
        __threadfence();
        __hip_atomic_fetch_add(&ctr[1], 1u, __ATOMIC_RELEASE, __HIP_MEMORY_SCOPE_AGENT);
        while (__hip_atomic_load(&ctr[1], __ATOMIC_ACQUIRE, __HIP_MEMORY_SCOPE_AGENT) < (unsigned)NBLK)
            __builtin_amdgcn_s_sleep(2);
    }
    __syncthreads();
    __threadfence();

    // ---- Phase C: every block redundantly folds all 2048 (m,s) pairs -> Z ----
    float fm = -1e30f, fs = 0.0f;
#pragma unroll
    for (int t = 0; t < 8; ++t) {
        int p = threadIdx.x + t * 256;
        lse_comb(fm, fs, pm[p], ps[p]);
    }
#pragma unroll
    for (int off = 1; off < 64; off <<= 1) {
        float om = __shfl_xor(fm, off, 64);
        float os = __shfl_xor(fs, off, 64);
        lse_comb(fm, fs, om, os);
    }
    if (lane == 0) { sm[w] = fm; ss[w] = fs; }
    __syncthreads();
    float M = sm[0], S = ss[0];
#pragma unroll
    for (int q = 1; q < 4; ++q) lse_comb(M, S, sm[q], ss[q]);
    float Z = M + logf(S);

    // ---- Phase D: write log-softmax from registers ----
    if (lane == 0) {
#pragma unroll
        for (int c = 0; c < 7; ++c) {
            int row = wave_id + c * NWAVE;
            if (row < VV) out[row] = lv[c] - Z;
        }
    }
}

extern "C" void kernel_launch(void* const* d_in, const int* in_sizes, int n_in,
                              void* d_out, int out_size, void* d_ws, size_t ws_size,
                              hipStream_t stream) {
    const int*   x     = (const int*)d_in[0];
    const float* h0    = (const float*)d_in[1];
    const float* c0    = (const float*)d_in[2];
    const float* emb   = (const float*)d_in[3];
    const float* w_ih  = (const float*)d_in[4];
    const float* w_hh  = (const float*)d_in[5];
    const float* b_ih  = (const float*)d_in[6];
    const float* b_hh  = (const float*)d_in[7];
    const float* w_out = (const float*)d_in[8];
    const float* b_out = (const float*)d_in[9];
    float* out = (float*)d_out;
    float* ws  = (float*)d_ws;

    float* hbuf = ws;                      // 1024 floats
    float* pm   = ws + 1024;               // 2048 floats
    float* ps   = ws + 1024 + 2048;        // 2048 floats
    unsigned int* ctr = (unsigned int*)(ws + 1024 + 4096);  // 2 u32, own line

    hipMemsetAsync(ctr, 0, 2 * sizeof(unsigned int), stream);
    k_fused<<<NBLK, 256, 0, stream>>>(x, emb, h0, c0, w_ih, w_hh, b_ih, b_hh,
                                      w_out, b_out, out, hbuf, pm, ps, ctr);
}

// Round 5
// 47.405 us; speedup vs baseline: 18.5331x; 18.5331x over previous
//
#include <hip/hip_runtime.h>
#include <math.h>

#define HH 1024
#define VV 50257
#define NLB 2048           // logits blocks
#define NWAVE (NLB * 4)    // 8192 logits waves; 50257 = 6*8192 + 1105

__device__ __forceinline__ float wave_allreduce_sum(float v) {
#pragma unroll
    for (int off = 1; off < 64; off <<= 1) v += __shfl_xor(v, off, 64);
    return v;
}

__device__ __forceinline__ void lse_comb(float& m, float& s, float om, float os) {
    float M = fmaxf(m, om);
    s = s * __expf(m - M) + os * __expf(om - M);
    m = M;
}

__device__ __forceinline__ float sigmoidf(float x) { return 1.0f / (1.0f + __expf(-x)); }

__device__ __forceinline__ float dot4(float4 a, float4 b) {
    return a.x * b.x + a.y * b.y + a.z * b.z + a.w * b.w;
}

// Kernel 1: fused gates+cell. 1024 blocks x 512 threads (full occupancy).
// Wave w: gate g=w>>1, half hf=w&1; each wave reduces 512 elements of both
// w_ih and w_hh rows; LDS-combine 8 partials; thread 0 runs the cell.
__global__ __launch_bounds__(512) void k_gatecell(
    const int* __restrict__ x, const float* __restrict__ emb,
    const float* __restrict__ h0, const float* __restrict__ c0,
    const float* __restrict__ w_ih, const float* __restrict__ w_hh,
    const float* __restrict__ b_ih, const float* __restrict__ b_hh,
    float* __restrict__ out) {
    __shared__ float sg2[8];
    const int j = blockIdx.x;
    const int w = threadIdx.x >> 6;
    const int lane = threadIdx.x & 63;
    const int g = w >> 1, hf = w & 1;
    const int row = g * HH + j;
    const int base = hf * 512 + lane * 8;

    const float* e  = emb + (size_t)x[0] * HH + base;
    const float* wi = w_ih + (size_t)row * HH + base;
    const float* wh = w_hh + (size_t)row * HH + base;
    const float* hp = h0 + base;

    float4 wi0 = *reinterpret_cast<const float4*>(wi);
    float4 wi1 = *reinterpret_cast<const float4*>(wi + 4);
    float4 wh0 = *reinterpret_cast<const float4*>(wh);
    float4 wh1 = *reinterpret_cast<const float4*>(wh + 4);
    float4 e0  = *reinterpret_cast<const float4*>(e);
    float4 e1  = *reinterpret_cast<const float4*>(e + 4);
    float4 hv0 = *reinterpret_cast<const float4*>(hp);
    float4 hv1 = *reinterpret_cast<const float4*>(hp + 4);
    e0.x = fmaxf(e0.x, 0.f); e0.y = fmaxf(e0.y, 0.f);
    e0.z = fmaxf(e0.z, 0.f); e0.w = fmaxf(e0.w, 0.f);
    e1.x = fmaxf(e1.x, 0.f); e1.y = fmaxf(e1.y, 0.f);
    e1.z = fmaxf(e1.z, 0.f); e1.w = fmaxf(e1.w, 0.f);

    float acc = dot4(wi0, e0) + dot4(wi1, e1) + dot4(wh0, hv0) + dot4(wh1, hv1);
    acc = wave_allreduce_sum(acc);
    if (lane == 0)
        sg2[w] = acc + (hf == 0 ? b_ih[row] + b_hh[row] : 0.0f);
    __syncthreads();
    if (threadIdx.x == 0) {
        float ig = sigmoidf(sg2[0] + sg2[1]);
        float fg = sigmoidf(sg2[2] + sg2[3]);
        float gg = tanhf(sg2[4] + sg2[5]);
        float og = sigmoidf(sg2[6] + sg2[7]);
        float c = fg * c0[j] + ig * gg;
        float h = og * tanhf(c);
        out[VV + j] = h;
        out[VV + HH + j] = c;
    }
}

// Kernel 2: logits + fused per-block online LSE. Wave per row, rows processed
// in PAIRS (8 dwordx4 in flight); h hoisted to registers; LSE wave-uniform.
__global__ __launch_bounds__(256) void k_logits_lse(
    const float* __restrict__ w_out, const float* __restrict__ b_out,
    const float* __restrict__ h, float* __restrict__ logits,
    float* __restrict__ pm, float* __restrict__ ps) {
    __shared__ float sm[4], ss[4];
    const int w = threadIdx.x >> 6;
    const int lane = threadIdx.x & 63;
    const int wid = blockIdx.x * 4 + w;

    // hoist h into 16 VGPRs
    const float* hp = h + lane * 4;
    float4 h0v = *reinterpret_cast<const float4*>(hp);
    float4 h1v = *reinterpret_cast<const float4*>(hp + 256);
    float4 h2v = *reinterpret_cast<const float4*>(hp + 512);
    float4 h3v = *reinterpret_cast<const float4*>(hp + 768);

    // prefetch biases (wave-uniform, L2-hot)
    float bo[7];
#pragma unroll
    for (int c = 0; c < 6; ++c) bo[c] = b_out[wid + c * NWAVE];
    {
        int r6 = wid + 6 * NWAVE;
        bo[6] = (r6 < VV) ? b_out[r6] : 0.0f;
    }

    const float* wb = w_out + (size_t)wid * HH + lane * 4;
    float m = -1e30f, s = 0.0f;

#pragma unroll
    for (int c = 0; c < 6; c += 2) {
        const float* pa = wb + (size_t)c * NWAVE * HH;
        const float* pb = pa + (size_t)NWAVE * HH;
        float4 a0 = *reinterpret_cast<const float4*>(pa);
        float4 a1 = *reinterpret_cast<const float4*>(pa + 256);
        float4 a2 = *reinterpret_cast<const float4*>(pa + 512);
        float4 a3 = *reinterpret_cast<const float4*>(pa + 768);
        float4 b0 = *reinterpret_cast<const float4*>(pb);
        float4 b1 = *reinterpret_cast<const float4*>(pb + 256);
        float4 b2 = *reinterpret_cast<const float4*>(pb + 512);
        float4 b3 = *reinterpret_cast<const float4*>(pb + 768);
        float accA = dot4(a0, h0v) + dot4(a1, h1v) + dot4(a2, h2v) + dot4(a3, h3v);
        float accB = dot4(b0, h0v) + dot4(b1, h1v) + dot4(b2, h2v) + dot4(b3, h3v);
        accA = wave_allreduce_sum(accA);
        accB = wave_allreduce_sum(accB);
        float vA = accA + bo[c];
        float vB = accB + bo[c + 1];
        if (lane == 0) {
            logits[wid + c * NWAVE] = vA;
            logits[wid + (c + 1) * NWAVE] = vB;
        }
        // wave-uniform online LSE
        if (vA > m) { s = s * __expf(m - vA) + 1.0f; m = vA; }
        else        { s += __expf(vA - m); }
        if (vB > m) { s = s * __expf(m - vB) + 1.0f; m = vB; }
        else        { s += __expf(vB - m); }
    }
    // tail chunk c=6 (only waves with wid < 1105)
    {
        int row = wid + 6 * NWAVE;
        if (row < VV) {
            const float* pa = wb + (size_t)6 * NWAVE * HH;
            float4 a0 = *reinterpret_cast<const float4*>(pa);
            float4 a1 = *reinterpret_cast<const float4*>(pa + 256);
            float4 a2 = *reinterpret_cast<const float4*>(pa + 512);
            float4 a3 = *reinterpret_cast<const float4*>(pa + 768);
            float acc = dot4(a0, h0v) + dot4(a1, h1v) + dot4(a2, h2v) + dot4(a3, h3v);
            acc = wave_allreduce_sum(acc);
            float v = acc + bo[6];
            if (lane == 0) logits[row] = v;
            if (v > m) { s = s * __expf(m - v) + 1.0f; m = v; }
            else       { s += __expf(v - m); }
        }
    }

    if (lane == 0) { sm[w] = m; ss[w] = s; }
    __syncthreads();
    if (threadIdx.x == 0) {
        float M = sm[0], S = ss[0];
#pragma unroll
        for (int q = 1; q < 4; ++q) lse_comb(M, S, sm[q], ss[q]);
        pm[blockIdx.x] = M;
        ps[blockIdx.x] = S;
    }
}

// Kernel 3: each block redundantly folds the NLB (m,s) pairs -> Z, then
// grid-strides out[v] = logits[v] - Z.
__global__ __launch_bounds__(256) void k_final(
    const float* __restrict__ logits, const float* __restrict__ pm,
    const float* __restrict__ ps, float* __restrict__ out) {
    __shared__ float sm[4], ss[4];
    __shared__ float sZ;
    int tid = threadIdx.x;
    int lane = tid & 63;
    float m = -1e30f, s = 0.0f;
    for (int p = tid; p < NLB; p += 256) {
        lse_comb(m, s, pm[p], ps[p]);
    }
#pragma unroll
    for (int off = 1; off < 64; off <<= 1) {
        float om = __shfl_xor(m, off, 64);
        float os = __shfl_xor(s, off, 64);
        lse_comb(m, s, om, os);
    }
    if (lane == 0) { sm[tid >> 6] = m; ss[tid >> 6] = s; }
    __syncthreads();
    if (tid == 0) {
        float M = sm[0], S = ss[0];
#pragma unroll
        for (int q = 1; q < 4; ++q) lse_comb(M, S, sm[q], ss[q]);
        sZ = M + logf(S);
    }
    __syncthreads();
    float Z = sZ;
    for (int i = blockIdx.x * 256 + tid; i < VV; i += gridDim.x * 256)
        out[i] = logits[i] - Z;
}

extern "C" void kernel_launch(void* const* d_in, const int* in_sizes, int n_in,
                              void* d_out, int out_size, void* d_ws, size_t ws_size,
                              hipStream_t stream) {
    const int*   x     = (const int*)d_in[0];
    const float* h0    = (const float*)d_in[1];
    const float* c0    = (const float*)d_in[2];
    const float* emb   = (const float*)d_in[3];
    const float* w_ih  = (const float*)d_in[4];
    const float* w_hh  = (const float*)d_in[5];
    const float* b_ih  = (const float*)d_in[6];
    const float* b_hh  = (const float*)d_in[7];
    const float* w_out = (const float*)d_in[8];
    const float* b_out = (const float*)d_in[9];
    float* out = (float*)d_out;
    float* ws  = (float*)d_ws;

    float* logits = ws;             // 50257 floats (pad to 50304)
    float* pm     = ws + 50304;     // NLB floats
    float* ps     = pm + NLB;       // NLB floats

    k_gatecell<<<HH, 512, 0, stream>>>(x, emb, h0, c0, w_ih, w_hh, b_ih, b_hh, out);
    k_logits_lse<<<NLB, 256, 0, stream>>>(w_out, b_out, out + VV, logits, pm, ps);
    k_final<<<256, 256, 0, stream>>>(logits, pm, ps, out);
}